// Round 1
// 457.358 us; speedup vs baseline: 1.1456x; 1.1456x over previous
//
#include <hip/hip_runtime.h>

#define NRAYS 4096
#define PSAMP 254      // 231 inner + 23 outer samples
#define NIN   231
#define GR    160
#define GR2   25600
#define GR3   4096000
#define SROW  136      // h-buffer row stride in bf16 elems (272 B, 16B-aligned, 4-bank rotation)

typedef __attribute__((ext_vector_type(8))) short bf16x8;
typedef __attribute__((ext_vector_type(4))) float f32x4;

__device__ __forceinline__ unsigned short f2bf(float x) {
    union { float f; unsigned u; } v; v.f = x;
    return (unsigned short)((v.u + 0x7fffu + ((v.u >> 16) & 1u)) >> 16);
}
__device__ __forceinline__ float sigmoidf_(float x) { return 1.0f / (1.0f + __expf(-x)); }

__device__ __forceinline__ unsigned packh2(float a, float b) {
    union { _Float16 h; unsigned short u; } ua, ub;
    ua.h = (_Float16)a; ub.h = (_Float16)b;
    return (unsigned)ua.u | ((unsigned)ub.u << 16);
}
__device__ __forceinline__ float h2f(unsigned u16) {
    union { unsigned short u; _Float16 h; } v; v.u = (unsigned short)u16;
    return (float)v.h;
}
// half c (0..7) out of a uint4 of 8 packed halfs
__device__ __forceinline__ float cget(const uint4& q, int c) {
    const unsigned w = ((const unsigned*)&q)[c >> 1];
    return h2f((c & 1) ? (w >> 16) : (w & 0xffffu));
}

// Pack W[K x N] (row-major fp32, row stride ldw) into MFMA B-fragment order, bf16.
__global__ void prepack(const float* __restrict__ w, unsigned short* __restrict__ out,
                        int K, int N, int ldw, int NT, int KS) {
    const int idx = blockIdx.x * 256 + threadIdx.x;
    if (idx >= NT * KS * 64) return;
    const int l  = idx & 63, f = idx >> 6;
    const int ks = f % KS,  nt = f / KS;
    const int n  = nt * 16 + (l & 15);
    const int k0 = ks * 32 + (l >> 4) * 8;
    unsigned p[4];
    #pragma unroll
    for (int q = 0; q < 4; q++) {
        const int ka = k0 + 2 * q, kb = ka + 1;
        const float va = (ka < K && n < N) ? w[ka * ldw + n] : 0.0f;
        const float vb = (kb < K && n < N) ? w[kb * ldw + n] : 0.0f;
        p[q] = (unsigned)f2bf(va) | ((unsigned)f2bf(vb) << 16);
    }
    uint4 v; v.x = p[0]; v.y = p[1]; v.z = p[2]; v.w = p[3];
    ((uint4*)out)[idx] = v;
}

// Repack density+k0 into channel-interleaved fp16: cell n -> 16 halfs at pg[n*16].
// ch0..11 = k0, ch12 = density, ch13..15 = 0. Total 160^3 * 32 B = 131 MB (L3-resident).
// Each thread handles 2 consecutive cells: 13 coalesced float2 loads + 64 B contiguous store.
__global__ __launch_bounds__(256) void repack_grid(
    const float* __restrict__ dg, const float* __restrict__ k0g,
    unsigned short* __restrict__ pg)
{
    const int i2 = blockIdx.x * 256 + threadIdx.x;
    if (i2 >= GR3 / 2) return;
    unsigned ow[16];
    #pragma unroll
    for (int c = 0; c < 12; c += 2) {
        const float2 va = ((const float2*)(k0g + (size_t)c       * GR3))[i2];
        const float2 vb = ((const float2*)(k0g + (size_t)(c + 1) * GR3))[i2];
        ow[(c >> 1)]     = packh2(va.x, vb.x);   // cell 2*i2
        ow[8 + (c >> 1)] = packh2(va.y, vb.y);   // cell 2*i2+1
    }
    const float2 dv = ((const float2*)dg)[i2];
    ow[6]  = packh2(dv.x, 0.0f);
    ow[14] = packh2(dv.y, 0.0f);
    ow[7] = 0u; ow[15] = 0u;
    uint4* dst = (uint4*)(pg + (size_t)i2 * 32);
    dst[0] = make_uint4(ow[0],  ow[1],  ow[2],  ow[3]);
    dst[1] = make_uint4(ow[4],  ow[5],  ow[6],  ow[7]);
    dst[2] = make_uint4(ow[8],  ow[9],  ow[10], ow[11]);
    dst[3] = make_uint4(ow[12], ow[13], ow[14], ow[15]);
}

__global__ __launch_bounds__(256, 2) void voxgo_mfma_pk(
    const float* __restrict__ rays_o, const float* __restrict__ rays_d,
    const float* __restrict__ viewdirs,
    const unsigned short* __restrict__ pg,
    const float* __restrict__ b0, const float* __restrict__ b1,
    const float* __restrict__ b2,
    const unsigned short* __restrict__ pw0, const unsigned short* __restrict__ pw1,
    const unsigned short* __restrict__ pw2,
    float* __restrict__ out)
{
    const int r    = blockIdx.x;
    const int tid  = threadIdx.x;
    const int wv   = tid >> 6, lane = tid & 63, quad = lane >> 4, l16 = lane & 15;

    __shared__ unsigned short hbuf[4][64 * SROW];
    __shared__ float sc[256];
    __shared__ float wgt[256];
    __shared__ float redbuf[256];

    // ================= phase 1: per-sample geometry =================
    const float ox = rays_o[3*r+0], oy = rays_o[3*r+1], oz = rays_o[3*r+2];
    float dxv = rays_d[3*r+0], dyv = rays_d[3*r+1], dzv = rays_d[3*r+2];
    const float vdx = viewdirs[3*r+0], vdy = viewdirs[3*r+1], vdz = viewdirs[3*r+2];
    const float rinv = rsqrtf(dxv*dxv + dyv*dyv + dzv*dzv);
    dxv *= rinv; dyv *= rinv; dzv *= rinv;

    float t;
    if (tid < NIN) {
        t = ((float)tid + 0.5f) * (2.0f * 1.7320508075688772f / 231.0f);
    } else {
        const float lstep = 0.999f / 23.0f;
        const int j = tid - NIN;                   // tids 254,255: finite junk; weight=0 kills it
        const float L0 = 1.0f - (float)j * lstep;
        const float L1 = 1.0f - (float)(j+1) * lstep;
        t = 1.7320508075688772f * (1.0f/L0 + 1.0f/L1);
    }

    float px = fmaf(dxv, t, ox), py = fmaf(dyv, t, oy), pz = fmaf(dzv, t, oz);
    const float nrm = fmaxf(fabsf(px), fmaxf(fabsf(py), fabsf(pz)));
    if (nrm > 1.0f) {
        const float s = (1.2f - 0.2f / nrm) / nrm;
        px *= s; py *= s; pz *= s;
    }

    const float gsc = 159.0f / 2.4f;
    const float gx = fminf(fmaxf((px + 1.2f) * gsc, 0.0f), 159.0f);
    const float gy = fminf(fmaxf((py + 1.2f) * gsc, 0.0f), 159.0f);
    const float gz = fminf(fmaxf((pz + 1.2f) * gsc, 0.0f), 159.0f);
    const int x0 = min((int)gx, GR-2), y0 = min((int)gy, GR-2), z0 = min((int)gz, GR-2);
    const float fx = gx - (float)x0, fy = gy - (float)y0, fz = gz - (float)z0;
    const int base = x0*GR2 + y0*GR + z0;

    // ===== issue the full corner-load clause: 8 corners x 32 B (hi half first: holds density) =====
    const unsigned short* cp = pg + (size_t)base * 16;
    uint4 hi[8], lo[8];
    #pragma unroll
    for (int j = 0; j < 8; j++) {
        const int off = ((j >> 2) * GR2 + ((j >> 1) & 1) * GR + (j & 1)) * 16;
        hi[j] = *((const uint4*)(cp + off) + 1);   // halfs 8..15 (ch8..11 + density ch12)
    }
    #pragma unroll
    for (int j = 0; j < 8; j++) {
        const int off = ((j >> 2) * GR2 + ((j >> 1) & 1) * GR + (j & 1)) * 16;
        lo[j] = *((const uint4*)(cp + off));       // halfs 0..7 (ch0..7)
    }

    // ===== viewdir embedding under the load shadow =====
    float fv[40];
    fv[12] = vdx; fv[13] = vdy; fv[14] = vdz;
    #pragma unroll
    for (int p = 0; p < 4; p++) {
        const float f = (float)(1 << p);
        fv[15+p] = __sinf(vdx*f);  fv[19+p] = __sinf(vdy*f);  fv[23+p] = __sinf(vdz*f);
        fv[27+p] = __cosf(vdx*f);  fv[31+p] = __cosf(vdy*f);  fv[35+p] = __cosf(vdz*f);
    }
    fv[39] = 0.0f;

    // ===== density interp (ch12 = word .z low half of hi) =====
    float dcr[8];
    #pragma unroll
    for (int j = 0; j < 8; j++) dcr[j] = h2f(hi[j].z & 0xffffu);
    const float c00 = dcr[0]*(1.0f-fz) + dcr[1]*fz;
    const float c01 = dcr[2]*(1.0f-fz) + dcr[3]*fz;
    const float c10 = dcr[4]*(1.0f-fz) + dcr[5]*fz;
    const float c11 = dcr[6]*(1.0f-fz) + dcr[7]*fz;
    const float dens = (c00*(1.0f-fy) + c01*fy)*(1.0f-fx) + (c10*(1.0f-fy) + c11*fy)*fx;

    const float ACT_SHIFT = -9.21024036697535f;    // log(1/(1-1e-4)-1)
    const float alpha = (tid < PSAMP) ? sigmoidf_(dens + ACT_SHIFT) : 0.0f;

    // ---- inclusive product scan of (1-alpha), fp32 ----
    sc[tid] = 1.0f - alpha;
    __syncthreads();
    #pragma unroll
    for (int off = 1; off < 256; off <<= 1) {
        const float v = (tid >= off) ? sc[tid - off] : 1.0f;
        __syncthreads();
        sc[tid] *= v;
        __syncthreads();
    }
    const float T_excl = (tid == 0) ? 1.0f : sc[tid-1];
    wgt[tid] = alpha * T_excl;

    // ================= phase 2: feat -> LDS bf16 (MFMA A-readable) =================
    const float wx0 = 1.0f-fx, wy0 = 1.0f-fy, wz0 = 1.0f-fz;
    const float w000 = wx0*wy0*wz0, w001 = wx0*wy0*fz, w010 = wx0*fy*wz0, w011 = wx0*fy*fz;
    const float w100 = fx*wy0*wz0,  w101 = fx*wy0*fz,  w110 = fx*fy*wz0,  w111 = fx*fy*fz;

    #pragma unroll
    for (int c = 0; c < 12; c++) {
        float s;
        if (c < 8) {
            s = w000*cget(lo[0],c) + w001*cget(lo[1],c)
              + w010*cget(lo[2],c) + w011*cget(lo[3],c)
              + w100*cget(lo[4],c) + w101*cget(lo[5],c)
              + w110*cget(lo[6],c) + w111*cget(lo[7],c);
        } else {
            s = w000*cget(hi[0],c-8) + w001*cget(hi[1],c-8)
              + w010*cget(hi[2],c-8) + w011*cget(hi[3],c-8)
              + w100*cget(hi[4],c-8) + w101*cget(hi[5],c-8)
              + w110*cget(hi[6],c-8) + w111*cget(hi[7],c-8);
        }
        fv[c] = s;
    }

    unsigned short* hb = &hbuf[wv][0];
    {
        const int row = tid & 63;
        uint4* dst = (uint4*)(hb + row * SROW);
        #pragma unroll
        for (int i = 0; i < 8; i++) {
            unsigned p[4];
            #pragma unroll
            for (int q = 0; q < 4; q++) {
                const int e0 = i*8 + 2*q, e1 = e0 + 1;
                const unsigned plo = (e0 < 39) ? f2bf(fv[e0]) : 0u;
                const unsigned phi = (e1 < 39) ? f2bf(fv[e1]) : 0u;
                p[q] = plo | (phi << 16);
            }
            uint4 v; v.x = p[0]; v.y = p[1]; v.z = p[2]; v.w = p[3];
            dst[i] = v;
        }
    }
    __syncthreads();

    // ================= phase 3: MLP via MFMA (per-wave, 64 samples each) =========
    // ---- layer 1: h1 = relu(feat @ w0 + b0)  (K=64 padded, N=128) ----
    f32x4 acc1[4][8];
    #pragma unroll
    for (int nt = 0; nt < 8; nt++) {
        const float bz = b0[nt*16 + l16];
        #pragma unroll
        for (int mt = 0; mt < 4; mt++) { f32x4 z = {bz,bz,bz,bz}; acc1[mt][nt] = z; }
    }
    #pragma unroll
    for (int ks = 0; ks < 2; ks++) {
        bf16x8 a[4];
        #pragma unroll
        for (int mt = 0; mt < 4; mt++)
            a[mt] = *(const bf16x8*)(hb + (mt*16 + l16)*SROW + ks*32 + quad*8);
        #pragma unroll
        for (int nt = 0; nt < 8; nt++) {
            const bf16x8 b = *(const bf16x8*)(pw0 + ((nt*2 + ks)*64 + lane)*8);
            #pragma unroll
            for (int mt = 0; mt < 4; mt++)
                acc1[mt][nt] = __builtin_amdgcn_mfma_f32_16x16x32_bf16(a[mt], b, acc1[mt][nt], 0,0,0);
        }
    }
    #pragma unroll
    for (int mt = 0; mt < 4; mt++)
        #pragma unroll
        for (int nt = 0; nt < 8; nt++)
            #pragma unroll
            for (int e = 0; e < 4; e++)
                hb[(mt*16 + quad*4 + e)*SROW + nt*16 + l16] = f2bf(fmaxf(acc1[mt][nt][e], 0.0f));
    __syncthreads();

    // ---- layer 2: h2 = relu(h1 @ w1 + b1)  (K=128, N=128) ----
    f32x4 acc2[4][8];
    #pragma unroll
    for (int nt = 0; nt < 8; nt++) {
        const float bz = b1[nt*16 + l16];
        #pragma unroll
        for (int mt = 0; mt < 4; mt++) { f32x4 z = {bz,bz,bz,bz}; acc2[mt][nt] = z; }
    }
    #pragma unroll
    for (int ks = 0; ks < 4; ks++) {
        bf16x8 a[4];
        #pragma unroll
        for (int mt = 0; mt < 4; mt++)
            a[mt] = *(const bf16x8*)(hb + (mt*16 + l16)*SROW + ks*32 + quad*8);
        #pragma unroll
        for (int nt = 0; nt < 8; nt++) {
            const bf16x8 b = *(const bf16x8*)(pw1 + ((nt*4 + ks)*64 + lane)*8);
            #pragma unroll
            for (int mt = 0; mt < 4; mt++)
                acc2[mt][nt] = __builtin_amdgcn_mfma_f32_16x16x32_bf16(a[mt], b, acc2[mt][nt], 0,0,0);
        }
    }
    #pragma unroll
    for (int mt = 0; mt < 4; mt++)
        #pragma unroll
        for (int nt = 0; nt < 8; nt++)
            #pragma unroll
            for (int e = 0; e < 4; e++)
                hb[(mt*16 + quad*4 + e)*SROW + nt*16 + l16] = f2bf(fmaxf(acc2[mt][nt][e], 0.0f));
    __syncthreads();

    // ---- layer 3: rgb_logit = h2 @ w2 + b2  (K=128, N=16 padded from 3) ----
    f32x4 acc3[4];
    {
        const float bz = (l16 < 3) ? b2[l16] : 0.0f;
        #pragma unroll
        for (int mt = 0; mt < 4; mt++) { f32x4 z = {bz,bz,bz,bz}; acc3[mt] = z; }
    }
    #pragma unroll
    for (int ks = 0; ks < 4; ks++) {
        const bf16x8 b = *(const bf16x8*)(pw2 + (ks*64 + lane)*8);
        #pragma unroll
        for (int mt = 0; mt < 4; mt++) {
            const bf16x8 a = *(const bf16x8*)(hb + (mt*16 + l16)*SROW + ks*32 + quad*8);
            acc3[mt] = __builtin_amdgcn_mfma_f32_16x16x32_bf16(a, b, acc3[mt], 0,0,0);
        }
    }

    // ================= epilogue: sigmoid + weighted reduce =================
    float contrib = 0.0f;
    #pragma unroll
    for (int mt = 0; mt < 4; mt++)
        #pragma unroll
        for (int e = 0; e < 4; e++) {
            const float s = sigmoidf_(acc3[mt][e]);
            contrib += wgt[wv*64 + mt*16 + quad*4 + e] * s;
        }
    redbuf[tid] = contrib;
    __syncthreads();
    if (tid < 3) {
        float acc_o = sc[PSAMP-1];                 // alphainv_last * BG(=1)
        #pragma unroll
        for (int w = 0; w < 4; w++)
            #pragma unroll
            for (int q = 0; q < 4; q++)
                acc_o += redbuf[w*64 + q*16 + tid];
        out[3*r + tid] = acc_o;
    }
}

// ===================== fallback (ws too small): previous verified kernel =====================
__global__ __launch_bounds__(256, 2) void voxgo_mfma_f32(
    const float* __restrict__ rays_o, const float* __restrict__ rays_d,
    const float* __restrict__ viewdirs, const float* __restrict__ dg,
    const float* __restrict__ k0g,
    const float* __restrict__ b0, const float* __restrict__ b1,
    const float* __restrict__ b2,
    const unsigned short* __restrict__ pw0, const unsigned short* __restrict__ pw1,
    const unsigned short* __restrict__ pw2,
    float* __restrict__ out)
{
    const int r    = blockIdx.x;
    const int tid  = threadIdx.x;
    const int wv   = tid >> 6, lane = tid & 63, quad = lane >> 4, l16 = lane & 15;

    __shared__ unsigned short hbuf[4][64 * SROW];
    __shared__ float sc[256];
    __shared__ float wgt[256];
    __shared__ float redbuf[256];

    const float ox = rays_o[3*r+0], oy = rays_o[3*r+1], oz = rays_o[3*r+2];
    float dxv = rays_d[3*r+0], dyv = rays_d[3*r+1], dzv = rays_d[3*r+2];
    const float vdx = viewdirs[3*r+0], vdy = viewdirs[3*r+1], vdz = viewdirs[3*r+2];
    const float rinv = rsqrtf(dxv*dxv + dyv*dyv + dzv*dzv);
    dxv *= rinv; dyv *= rinv; dzv *= rinv;

    float t;
    if (tid < NIN) {
        t = ((float)tid + 0.5f) * (2.0f * 1.7320508075688772f / 231.0f);
    } else {
        const float lstep = 0.999f / 23.0f;
        const int j = tid - NIN;
        const float L0 = 1.0f - (float)j * lstep;
        const float L1 = 1.0f - (float)(j+1) * lstep;
        t = 1.7320508075688772f * (1.0f/L0 + 1.0f/L1);
    }

    float px = fmaf(dxv, t, ox), py = fmaf(dyv, t, oy), pz = fmaf(dzv, t, oz);
    const float nrm = fmaxf(fabsf(px), fmaxf(fabsf(py), fabsf(pz)));
    if (nrm > 1.0f) {
        const float s = (1.2f - 0.2f / nrm) / nrm;
        px *= s; py *= s; pz *= s;
    }

    const float gsc = 159.0f / 2.4f;
    const float gx = fminf(fmaxf((px + 1.2f) * gsc, 0.0f), 159.0f);
    const float gy = fminf(fmaxf((py + 1.2f) * gsc, 0.0f), 159.0f);
    const float gz = fminf(fmaxf((pz + 1.2f) * gsc, 0.0f), 159.0f);
    const int x0 = min((int)gx, GR-2), y0 = min((int)gy, GR-2), z0 = min((int)gz, GR-2);
    const float fx = gx - (float)x0, fy = gy - (float)y0, fz = gz - (float)z0;
    const int base = x0*GR2 + y0*GR + z0;

    const float d000 = dg[base],        d001 = dg[base+1];
    const float d010 = dg[base+GR],     d011 = dg[base+GR+1];
    const float d100 = dg[base+GR2],    d101 = dg[base+GR2+1];
    const float d110 = dg[base+GR2+GR], d111 = dg[base+GR2+GR+1];
    const float c00 = d000*(1.0f-fz) + d001*fz;
    const float c01 = d010*(1.0f-fz) + d011*fz;
    const float c10 = d100*(1.0f-fz) + d101*fz;
    const float c11 = d110*(1.0f-fz) + d111*fz;
    const float dens = (c00*(1.0f-fy) + c01*fy)*(1.0f-fx) + (c10*(1.0f-fy) + c11*fy)*fx;

    const float ACT_SHIFT = -9.21024036697535f;
    const float alpha = (tid < PSAMP) ? sigmoidf_(dens + ACT_SHIFT) : 0.0f;

    sc[tid] = 1.0f - alpha;
    __syncthreads();
    #pragma unroll
    for (int off = 1; off < 256; off <<= 1) {
        const float v = (tid >= off) ? sc[tid - off] : 1.0f;
        __syncthreads();
        sc[tid] *= v;
        __syncthreads();
    }
    const float T_excl = (tid == 0) ? 1.0f : sc[tid-1];
    wgt[tid] = alpha * T_excl;

    const float wx0 = 1.0f-fx, wy0 = 1.0f-fy, wz0 = 1.0f-fz;
    const float w000 = wx0*wy0*wz0, w001 = wx0*wy0*fz, w010 = wx0*fy*wz0, w011 = wx0*fy*fz;
    const float w100 = fx*wy0*wz0,  w101 = fx*wy0*fz,  w110 = fx*fy*wz0,  w111 = fx*fy*fz;

    float fv[40];
    #pragma unroll
    for (int c = 0; c < 12; c++) {
        const float* g = k0g + c*GR3 + base;
        fv[c] = w000*g[0]      + w001*g[1]
              + w010*g[GR]     + w011*g[GR+1]
              + w100*g[GR2]    + w101*g[GR2+1]
              + w110*g[GR2+GR] + w111*g[GR2+GR+1];
    }
    fv[12] = vdx; fv[13] = vdy; fv[14] = vdz;
    #pragma unroll
    for (int p = 0; p < 4; p++) {
        const float f = (float)(1 << p);
        fv[15+p] = __sinf(vdx*f);  fv[19+p] = __sinf(vdy*f);  fv[23+p] = __sinf(vdz*f);
        fv[27+p] = __cosf(vdx*f);  fv[31+p] = __cosf(vdy*f);  fv[35+p] = __cosf(vdz*f);
    }
    fv[39] = 0.0f;

    unsigned short* hb = &hbuf[wv][0];
    {
        const int row = tid & 63;
        uint4* dst = (uint4*)(hb + row * SROW);
        #pragma unroll
        for (int i = 0; i < 8; i++) {
            unsigned p[4];
            #pragma unroll
            for (int q = 0; q < 4; q++) {
                const int e0 = i*8 + 2*q, e1 = e0 + 1;
                const unsigned lov = (e0 < 39) ? f2bf(fv[e0]) : 0u;
                const unsigned hiv = (e1 < 39) ? f2bf(fv[e1]) : 0u;
                p[q] = lov | (hiv << 16);
            }
            uint4 v; v.x = p[0]; v.y = p[1]; v.z = p[2]; v.w = p[3];
            dst[i] = v;
        }
    }
    __syncthreads();

    f32x4 acc1[4][8];
    #pragma unroll
    for (int nt = 0; nt < 8; nt++) {
        const float bz = b0[nt*16 + l16];
        #pragma unroll
        for (int mt = 0; mt < 4; mt++) { f32x4 z = {bz,bz,bz,bz}; acc1[mt][nt] = z; }
    }
    #pragma unroll
    for (int ks = 0; ks < 2; ks++) {
        bf16x8 a[4];
        #pragma unroll
        for (int mt = 0; mt < 4; mt++)
            a[mt] = *(const bf16x8*)(hb + (mt*16 + l16)*SROW + ks*32 + quad*8);
        #pragma unroll
        for (int nt = 0; nt < 8; nt++) {
            const bf16x8 b = *(const bf16x8*)(pw0 + ((nt*2 + ks)*64 + lane)*8);
            #pragma unroll
            for (int mt = 0; mt < 4; mt++)
                acc1[mt][nt] = __builtin_amdgcn_mfma_f32_16x16x32_bf16(a[mt], b, acc1[mt][nt], 0,0,0);
        }
    }
    #pragma unroll
    for (int mt = 0; mt < 4; mt++)
        #pragma unroll
        for (int nt = 0; nt < 8; nt++)
            #pragma unroll
            for (int e = 0; e < 4; e++)
                hb[(mt*16 + quad*4 + e)*SROW + nt*16 + l16] = f2bf(fmaxf(acc1[mt][nt][e], 0.0f));
    __syncthreads();

    f32x4 acc2[4][8];
    #pragma unroll
    for (int nt = 0; nt < 8; nt++) {
        const float bz = b1[nt*16 + l16];
        #pragma unroll
        for (int mt = 0; mt < 4; mt++) { f32x4 z = {bz,bz,bz,bz}; acc2[mt][nt] = z; }
    }
    #pragma unroll
    for (int ks = 0; ks < 4; ks++) {
        bf16x8 a[4];
        #pragma unroll
        for (int mt = 0; mt < 4; mt++)
            a[mt] = *(const bf16x8*)(hb + (mt*16 + l16)*SROW + ks*32 + quad*8);
        #pragma unroll
        for (int nt = 0; nt < 8; nt++) {
            const bf16x8 b = *(const bf16x8*)(pw1 + ((nt*4 + ks)*64 + lane)*8);
            #pragma unroll
            for (int mt = 0; mt < 4; mt++)
                acc2[mt][nt] = __builtin_amdgcn_mfma_f32_16x16x32_bf16(a[mt], b, acc2[mt][nt], 0,0,0);
        }
    }
    #pragma unroll
    for (int mt = 0; mt < 4; mt++)
        #pragma unroll
        for (int nt = 0; nt < 8; nt++)
            #pragma unroll
            for (int e = 0; e < 4; e++)
                hb[(mt*16 + quad*4 + e)*SROW + nt*16 + l16] = f2bf(fmaxf(acc2[mt][nt][e], 0.0f));
    __syncthreads();

    f32x4 acc3[4];
    {
        const float bz = (l16 < 3) ? b2[l16] : 0.0f;
        #pragma unroll
        for (int mt = 0; mt < 4; mt++) { f32x4 z = {bz,bz,bz,bz}; acc3[mt] = z; }
    }
    #pragma unroll
    for (int ks = 0; ks < 4; ks++) {
        const bf16x8 b = *(const bf16x8*)(pw2 + (ks*64 + lane)*8);
        #pragma unroll
        for (int mt = 0; mt < 4; mt++) {
            const bf16x8 a = *(const bf16x8*)(hb + (mt*16 + l16)*SROW + ks*32 + quad*8);
            acc3[mt] = __builtin_amdgcn_mfma_f32_16x16x32_bf16(a, b, acc3[mt], 0,0,0);
        }
    }

    float contrib = 0.0f;
    #pragma unroll
    for (int mt = 0; mt < 4; mt++)
        #pragma unroll
        for (int e = 0; e < 4; e++) {
            const float s = sigmoidf_(acc3[mt][e]);
            contrib += wgt[wv*64 + mt*16 + quad*4 + e] * s;
        }
    redbuf[tid] = contrib;
    __syncthreads();
    if (tid < 3) {
        float acc_o = sc[PSAMP-1];
        #pragma unroll
        for (int w = 0; w < 4; w++)
            #pragma unroll
            for (int q = 0; q < 4; q++)
                acc_o += redbuf[w*64 + q*16 + tid];
        out[3*r + tid] = acc_o;
    }
}

extern "C" void kernel_launch(void* const* d_in, const int* in_sizes, int n_in,
                              void* d_out, int out_size, void* d_ws, size_t ws_size,
                              hipStream_t stream) {
    (void)in_sizes; (void)n_in; (void)out_size;
    const size_t PG_BYTES = (size_t)GR3 * 32;            // 131,072,000 B packed fp16 grid
    const size_t PW_BYTES = (size_t)(16 + 32 + 4) * 64 * 8 * 2;   // 53,248 B packed weights

    if (ws_size >= PG_BYTES + PW_BYTES) {
        unsigned short* pg  = (unsigned short*)d_ws;
        unsigned short* pw0 = (unsigned short*)((char*)d_ws + PG_BYTES);
        unsigned short* pw1 = pw0 + 16*64*8;
        unsigned short* pw2 = pw1 + 32*64*8;

        repack_grid<<<GR3/512, 256, 0, stream>>>(
            (const float*)d_in[3], (const float*)d_in[4], pg);
        prepack<<<4, 256, 0, stream>>>((const float*)d_in[5], pw0,  39, 128, 128, 8, 2);
        prepack<<<8, 256, 0, stream>>>((const float*)d_in[7], pw1, 128, 128, 128, 8, 4);
        prepack<<<1, 256, 0, stream>>>((const float*)d_in[9], pw2, 128,   3,   3, 1, 4);

        voxgo_mfma_pk<<<NRAYS, 256, 0, stream>>>(
            (const float*)d_in[0], (const float*)d_in[1], (const float*)d_in[2],
            pg,
            (const float*)d_in[6], (const float*)d_in[8], (const float*)d_in[10],
            pw0, pw1, pw2,
            (float*)d_out);
    } else {
        unsigned short* pw0 = (unsigned short*)d_ws;
        unsigned short* pw1 = pw0 + 16*64*8;
        unsigned short* pw2 = pw1 + 32*64*8;

        prepack<<<4, 256, 0, stream>>>((const float*)d_in[5], pw0,  39, 128, 128, 8, 2);
        prepack<<<8, 256, 0, stream>>>((const float*)d_in[7], pw1, 128, 128, 128, 8, 4);
        prepack<<<1, 256, 0, stream>>>((const float*)d_in[9], pw2, 128,   3,   3, 1, 4);

        voxgo_mfma_f32<<<NRAYS, 256, 0, stream>>>(
            (const float*)d_in[0], (const float*)d_in[1], (const float*)d_in[2],
            (const float*)d_in[3], (const float*)d_in[4],
            (const float*)d_in[6], (const float*)d_in[8], (const float*)d_in[10],
            pw0, pw1, pw2,
            (float*)d_out);
    }
}

// Round 2
// 438.378 us; speedup vs baseline: 1.1952x; 1.0433x over previous
//
#include <hip/hip_runtime.h>

#define NRAYS 4096
#define PSAMP 254      // 231 inner + 23 outer samples
#define NIN   231
#define GR    160
#define GR2   25600
#define GR3   4096000
#define SROW  136      // h-buffer row stride in bf16 elems (272 B, 16B-aligned)

typedef __attribute__((ext_vector_type(8))) short bf16x8;
typedef __attribute__((ext_vector_type(4))) float f32x4;

__device__ __forceinline__ unsigned short f2bf(float x) {
    union { float f; unsigned u; } v; v.f = x;
    return (unsigned short)((v.u + 0x7fffu + ((v.u >> 16) & 1u)) >> 16);
}
__device__ __forceinline__ float sigmoidf_(float x) { return 1.0f / (1.0f + __expf(-x)); }

// packed bf16 pair via HW cvt (RNE), low = a, high = b
__device__ __forceinline__ unsigned cvt_pk_bf16(float a, float b) {
    unsigned r;
    asm("v_cvt_pk_bf16_f32 %0, %1, %2" : "=v"(r) : "v"(a), "v"(b));
    return r;
}

__device__ __forceinline__ unsigned packh2(float a, float b) {
    union { _Float16 h; unsigned short u; } ua, ub;
    ua.h = (_Float16)a; ub.h = (_Float16)b;
    return (unsigned)ua.u | ((unsigned)ub.u << 16);
}
__device__ __forceinline__ float h2f(unsigned u16) {
    union { unsigned short u; _Float16 h; } v; v.u = (unsigned short)u16;
    return (float)v.h;
}
__device__ __forceinline__ float cget(const uint4& q, int c) {
    const unsigned w = ((const unsigned*)&q)[c >> 1];
    return h2f((c & 1) ? (w >> 16) : (w & 0xffffu));
}

// Pack W[K x N] (row-major fp32, row stride ldw) into MFMA fragment order, bf16.
// Lane l of frag f=(nt*KS+ks) holds W[k=ks*32+(l>>4)*8+j][n=nt*16+(l&15)].
// Usable as B-frag (n=col) OR as A-frag of W^T (n=row) — layouts are symmetric.
__global__ void prepack(const float* __restrict__ w, unsigned short* __restrict__ out,
                        int K, int N, int ldw, int NT, int KS) {
    const int idx = blockIdx.x * 256 + threadIdx.x;
    if (idx >= NT * KS * 64) return;
    const int l  = idx & 63, f = idx >> 6;
    const int ks = f % KS,  nt = f / KS;
    const int n  = nt * 16 + (l & 15);
    const int k0 = ks * 32 + (l >> 4) * 8;
    unsigned p[4];
    #pragma unroll
    for (int q = 0; q < 4; q++) {
        const int ka = k0 + 2 * q, kb = ka + 1;
        const float va = (ka < K && n < N) ? w[ka * ldw + n] : 0.0f;
        const float vb = (kb < K && n < N) ? w[kb * ldw + n] : 0.0f;
        p[q] = (unsigned)f2bf(va) | ((unsigned)f2bf(vb) << 16);
    }
    uint4 v; v.x = p[0]; v.y = p[1]; v.z = p[2]; v.w = p[3];
    ((uint4*)out)[idx] = v;
}

// Repack density+k0 into channel-interleaved fp16: cell n -> 16 halfs at pg[n*16].
// ch0..11 = k0, ch12 = density, ch13..15 = 0. 160^3 * 32 B = 131 MB (L3-resident).
__global__ __launch_bounds__(256) void repack_grid(
    const float* __restrict__ dg, const float* __restrict__ k0g,
    unsigned short* __restrict__ pg)
{
    const int i2 = blockIdx.x * 256 + threadIdx.x;
    if (i2 >= GR3 / 2) return;
    unsigned ow[16];
    #pragma unroll
    for (int c = 0; c < 12; c += 2) {
        const float2 va = ((const float2*)(k0g + (size_t)c       * GR3))[i2];
        const float2 vb = ((const float2*)(k0g + (size_t)(c + 1) * GR3))[i2];
        ow[(c >> 1)]     = packh2(va.x, vb.x);
        ow[8 + (c >> 1)] = packh2(va.y, vb.y);
    }
    const float2 dv = ((const float2*)dg)[i2];
    ow[6]  = packh2(dv.x, 0.0f);
    ow[14] = packh2(dv.y, 0.0f);
    ow[7] = 0u; ow[15] = 0u;
    uint4* dst = (uint4*)(pg + (size_t)i2 * 32);
    dst[0] = make_uint4(ow[0],  ow[1],  ow[2],  ow[3]);
    dst[1] = make_uint4(ow[4],  ow[5],  ow[6],  ow[7]);
    dst[2] = make_uint4(ow[8],  ow[9],  ow[10], ow[11]);
    dst[3] = make_uint4(ow[12], ow[13], ow[14], ow[15]);
}

// Transposed-MFMA main kernel: compute h^T = W^T · x^T so each lane owns 4
// consecutive FEATURES of one SAMPLE -> packed b64 LDS writebacks, and the
// per-wave h-buffer needs no block barriers (2 barriers total in kernel).
__global__ __launch_bounds__(256, 2) void voxgo_mfma_pk(
    const float* __restrict__ rays_o, const float* __restrict__ rays_d,
    const float* __restrict__ viewdirs,
    const unsigned short* __restrict__ pg,
    const float* __restrict__ b0, const float* __restrict__ b1,
    const float* __restrict__ b2,
    const unsigned short* __restrict__ pw0, const unsigned short* __restrict__ pw1,
    const unsigned short* __restrict__ pw2,
    float* __restrict__ out)
{
    const int r    = blockIdx.x;
    const int tid  = threadIdx.x;
    const int wv   = tid >> 6, lane = tid & 63, quad = lane >> 4, l16 = lane & 15;

    __shared__ unsigned short hbuf[4][64 * SROW];  // per-wave: feat, then h1, then h2
    __shared__ float wgt[256];                     // per-sample weights
    __shared__ float redbuf[4 * 16 * 3];           // per-(wave,l16) rgb partials
    __shared__ float wtot[4];                      // per-wave (1-alpha) products

    // ================= phase 1: per-sample geometry =================
    const float ox = rays_o[3*r+0], oy = rays_o[3*r+1], oz = rays_o[3*r+2];
    float dxv = rays_d[3*r+0], dyv = rays_d[3*r+1], dzv = rays_d[3*r+2];
    const float vdx = viewdirs[3*r+0], vdy = viewdirs[3*r+1], vdz = viewdirs[3*r+2];
    const float rinv = rsqrtf(dxv*dxv + dyv*dyv + dzv*dzv);
    dxv *= rinv; dyv *= rinv; dzv *= rinv;

    float t;
    if (tid < NIN) {
        t = ((float)tid + 0.5f) * (2.0f * 1.7320508075688772f / 231.0f);
    } else {
        const float lstep = 0.999f / 23.0f;
        const int j = tid - NIN;                   // tids 254,255: finite junk; weight=0 kills it
        const float L0 = 1.0f - (float)j * lstep;
        const float L1 = 1.0f - (float)(j+1) * lstep;
        t = 1.7320508075688772f * (1.0f/L0 + 1.0f/L1);
    }

    float px = fmaf(dxv, t, ox), py = fmaf(dyv, t, oy), pz = fmaf(dzv, t, oz);
    const float nrm = fmaxf(fabsf(px), fmaxf(fabsf(py), fabsf(pz)));
    if (nrm > 1.0f) {
        const float s = (1.2f - 0.2f / nrm) / nrm;
        px *= s; py *= s; pz *= s;
    }

    const float gsc = 159.0f / 2.4f;
    const float gx = fminf(fmaxf((px + 1.2f) * gsc, 0.0f), 159.0f);
    const float gy = fminf(fmaxf((py + 1.2f) * gsc, 0.0f), 159.0f);
    const float gz = fminf(fmaxf((pz + 1.2f) * gsc, 0.0f), 159.0f);
    const int x0 = min((int)gx, GR-2), y0 = min((int)gy, GR-2), z0 = min((int)gz, GR-2);
    const float fx = gx - (float)x0, fy = gy - (float)y0, fz = gz - (float)z0;
    const int base = x0*GR2 + y0*GR + z0;

    // ===== corner-load clause: 8 corners x 32 B (hi half first: holds density) =====
    const unsigned short* cp = pg + (size_t)base * 16;
    uint4 hi[8], lo[8];
    #pragma unroll
    for (int j = 0; j < 8; j++) {
        const int off = ((j >> 2) * GR2 + ((j >> 1) & 1) * GR + (j & 1)) * 16;
        hi[j] = *((const uint4*)(cp + off) + 1);   // halfs 8..15 (ch8..11 + density ch12)
    }
    #pragma unroll
    for (int j = 0; j < 8; j++) {
        const int off = ((j >> 2) * GR2 + ((j >> 1) & 1) * GR + (j & 1)) * 16;
        lo[j] = *((const uint4*)(cp + off));       // halfs 0..7 (ch0..7)
    }

    // ===== viewdir embedding under the load shadow =====
    float fv[40];
    fv[12] = vdx; fv[13] = vdy; fv[14] = vdz;
    #pragma unroll
    for (int p = 0; p < 4; p++) {
        const float f = (float)(1 << p);
        fv[15+p] = __sinf(vdx*f);  fv[19+p] = __sinf(vdy*f);  fv[23+p] = __sinf(vdz*f);
        fv[27+p] = __cosf(vdx*f);  fv[31+p] = __cosf(vdy*f);  fv[35+p] = __cosf(vdz*f);
    }
    fv[39] = 0.0f;

    // ===== density interp (ch12 = word .z low half of hi) =====
    float dcr[8];
    #pragma unroll
    for (int j = 0; j < 8; j++) dcr[j] = h2f(hi[j].z & 0xffffu);
    const float c00 = dcr[0]*(1.0f-fz) + dcr[1]*fz;
    const float c01 = dcr[2]*(1.0f-fz) + dcr[3]*fz;
    const float c10 = dcr[4]*(1.0f-fz) + dcr[5]*fz;
    const float c11 = dcr[6]*(1.0f-fz) + dcr[7]*fz;
    const float dens = (c00*(1.0f-fy) + c01*fy)*(1.0f-fx) + (c10*(1.0f-fy) + c11*fy)*fx;

    const float ACT_SHIFT = -9.21024036697535f;    // log(1/(1-1e-4)-1)
    const float alpha = (tid < PSAMP) ? sigmoidf_(dens + ACT_SHIFT) : 0.0f;

    // ---- inclusive product scan: 6-step wave shuffle + cross-wave combine ----
    float vscan = 1.0f - alpha;
    #pragma unroll
    for (int off = 1; off < 64; off <<= 1) {
        const float u = __shfl_up(vscan, off);
        if (lane >= off) vscan *= u;
    }
    if (lane == 63) wtot[wv] = vscan;
    __syncthreads();                               // barrier 1 of 2
    float pre = 1.0f;
    #pragma unroll
    for (int w = 0; w < 3; w++) if (w < wv) pre *= wtot[w];
    const float eprev = __shfl_up(vscan, 1);
    const float T_excl = (lane == 0) ? pre : pre * eprev;
    wgt[tid] = alpha * T_excl;                     // read later only by same wave

    // ================= phase 2: feat -> LDS bf16 =================
    const float wx0 = 1.0f-fx, wy0 = 1.0f-fy, wz0 = 1.0f-fz;
    const float w000 = wx0*wy0*wz0, w001 = wx0*wy0*fz, w010 = wx0*fy*wz0, w011 = wx0*fy*fz;
    const float w100 = fx*wy0*wz0,  w101 = fx*wy0*fz,  w110 = fx*fy*wz0,  w111 = fx*fy*fz;

    #pragma unroll
    for (int c = 0; c < 12; c++) {
        float s;
        if (c < 8) {
            s = w000*cget(lo[0],c) + w001*cget(lo[1],c)
              + w010*cget(lo[2],c) + w011*cget(lo[3],c)
              + w100*cget(lo[4],c) + w101*cget(lo[5],c)
              + w110*cget(lo[6],c) + w111*cget(lo[7],c);
        } else {
            s = w000*cget(hi[0],c-8) + w001*cget(hi[1],c-8)
              + w010*cget(hi[2],c-8) + w011*cget(hi[3],c-8)
              + w100*cget(hi[4],c-8) + w101*cget(hi[5],c-8)
              + w110*cget(hi[6],c-8) + w111*cget(hi[7],c-8);
        }
        fv[c] = s;
    }

    unsigned short* hb = &hbuf[wv][0];
    {
        const int row = tid & 63;
        uint4* dst = (uint4*)(hb + row * SROW);
        #pragma unroll
        for (int i = 0; i < 8; i++) {
            unsigned p[4];
            #pragma unroll
            for (int q = 0; q < 4; q++) {
                const int e0 = i*8 + 2*q, e1 = e0 + 1;
                const float a = (e0 < 39) ? fv[e0] : 0.0f;
                const float b = (e1 < 39) ? fv[e1] : 0.0f;
                p[q] = cvt_pk_bf16(a, b);
            }
            uint4 v; v.x = p[0]; v.y = p[1]; v.z = p[2]; v.w = p[3];
            dst[i] = v;
        }
    }
    // NO block barrier: hbuf[wv] is private to this wave; intra-wave LDS
    // ordering is enforced by compiler-inserted lgkmcnt.

    // ================= phase 3: MLP, transposed (h^T = W^T x^T) =================
    // A-frag = prepacked W (row=out-feature), B-frag: lane(quad,l16) reads 8
    // consecutive in-features of sample (st*16+l16). C: row=out-feature
    // (quad*4+e + 16*ft), col=sample (l16 + 16*st).

    // ---- layer 1: h1^T = relu(w0^T feat^T + b0) (K=64 padded, 128 features) ----
    f32x4 acc1[8][4];
    #pragma unroll
    for (int ft = 0; ft < 8; ft++) {
        const f32x4 bv = *(const f32x4*)(b0 + ft*16 + quad*4);
        #pragma unroll
        for (int st = 0; st < 4; st++) acc1[ft][st] = bv;
    }
    #pragma unroll
    for (int ks = 0; ks < 2; ks++) {
        bf16x8 bfr[4];
        #pragma unroll
        for (int st = 0; st < 4; st++)
            bfr[st] = *(const bf16x8*)(hb + (st*16 + l16)*SROW + ks*32 + quad*8);
        #pragma unroll
        for (int ft = 0; ft < 8; ft++) {
            const bf16x8 afr = *(const bf16x8*)(pw0 + ((ft*2 + ks)*64 + lane)*8);
            #pragma unroll
            for (int st = 0; st < 4; st++)
                acc1[ft][st] = __builtin_amdgcn_mfma_f32_16x16x32_bf16(afr, bfr[st], acc1[ft][st], 0,0,0);
        }
    }
    #pragma unroll
    for (int ft = 0; ft < 8; ft++)
        #pragma unroll
        for (int st = 0; st < 4; st++) {
            const f32x4 a = acc1[ft][st];
            uint2 v;
            v.x = cvt_pk_bf16(fmaxf(a[0], 0.0f), fmaxf(a[1], 0.0f));
            v.y = cvt_pk_bf16(fmaxf(a[2], 0.0f), fmaxf(a[3], 0.0f));
            *(uint2*)(hb + (st*16 + l16)*SROW + ft*16 + quad*4) = v;
        }

    // ---- layer 2: h2^T = relu(w1^T h1^T + b1) (K=128, 128 features) ----
    f32x4 acc2[8][4];
    #pragma unroll
    for (int ft = 0; ft < 8; ft++) {
        const f32x4 bv = *(const f32x4*)(b1 + ft*16 + quad*4);
        #pragma unroll
        for (int st = 0; st < 4; st++) acc2[ft][st] = bv;
    }
    #pragma unroll
    for (int ks = 0; ks < 4; ks++) {
        bf16x8 bfr[4];
        #pragma unroll
        for (int st = 0; st < 4; st++)
            bfr[st] = *(const bf16x8*)(hb + (st*16 + l16)*SROW + ks*32 + quad*8);
        #pragma unroll
        for (int ft = 0; ft < 8; ft++) {
            const bf16x8 afr = *(const bf16x8*)(pw1 + ((ft*4 + ks)*64 + lane)*8);
            #pragma unroll
            for (int st = 0; st < 4; st++)
                acc2[ft][st] = __builtin_amdgcn_mfma_f32_16x16x32_bf16(afr, bfr[st], acc2[ft][st], 0,0,0);
        }
    }
    #pragma unroll
    for (int ft = 0; ft < 8; ft++)
        #pragma unroll
        for (int st = 0; st < 4; st++) {
            const f32x4 a = acc2[ft][st];
            uint2 v;
            v.x = cvt_pk_bf16(fmaxf(a[0], 0.0f), fmaxf(a[1], 0.0f));
            v.y = cvt_pk_bf16(fmaxf(a[2], 0.0f), fmaxf(a[3], 0.0f));
            *(uint2*)(hb + (st*16 + l16)*SROW + ft*16 + quad*4) = v;
        }

    // ---- layer 3: rgb^T = w2^T h2^T + b2 (K=128, rows 0..2 valid) ----
    f32x4 acc3[4];
    {
        f32x4 bz3; bz3[0] = b2[0]; bz3[1] = b2[1]; bz3[2] = b2[2]; bz3[3] = 0.0f;
        #pragma unroll
        for (int st = 0; st < 4; st++) acc3[st] = bz3;   // rows>=3 garbage, never read
    }
    #pragma unroll
    for (int ks = 0; ks < 4; ks++) {
        const bf16x8 afr = *(const bf16x8*)(pw2 + (ks*64 + lane)*8);
        #pragma unroll
        for (int st = 0; st < 4; st++) {
            const bf16x8 bfr = *(const bf16x8*)(hb + (st*16 + l16)*SROW + ks*32 + quad*8);
            acc3[st] = __builtin_amdgcn_mfma_f32_16x16x32_bf16(afr, bfr, acc3[st], 0,0,0);
        }
    }

    // ================= epilogue: sigmoid + weighted reduce =================
    if (quad == 0) {                               // rows 0..2 = rgb channels
        float c0 = 0.0f, c1 = 0.0f, c2 = 0.0f;
        #pragma unroll
        for (int st = 0; st < 4; st++) {
            const float w = wgt[wv*64 + st*16 + l16];
            c0 += w * sigmoidf_(acc3[st][0]);
            c1 += w * sigmoidf_(acc3[st][1]);
            c2 += w * sigmoidf_(acc3[st][2]);
        }
        float* rb = &redbuf[(wv*16 + l16)*3];
        rb[0] = c0; rb[1] = c1; rb[2] = c2;
    }
    __syncthreads();                               // barrier 2 of 2
    if (tid < 3) {
        float acc_o = wtot[0]*wtot[1]*wtot[2]*wtot[3];   // alphainv_last * BG(=1)
        #pragma unroll 4
        for (int i = 0; i < 64; i++) acc_o += redbuf[i*3 + tid];
        out[3*r + tid] = acc_o;
    }
}

// ===================== fallback (ws too small): previous verified kernel =====================
__global__ __launch_bounds__(256, 2) void voxgo_mfma_f32(
    const float* __restrict__ rays_o, const float* __restrict__ rays_d,
    const float* __restrict__ viewdirs, const float* __restrict__ dg,
    const float* __restrict__ k0g,
    const float* __restrict__ b0, const float* __restrict__ b1,
    const float* __restrict__ b2,
    const unsigned short* __restrict__ pw0, const unsigned short* __restrict__ pw1,
    const unsigned short* __restrict__ pw2,
    float* __restrict__ out)
{
    const int r    = blockIdx.x;
    const int tid  = threadIdx.x;
    const int wv   = tid >> 6, lane = tid & 63, quad = lane >> 4, l16 = lane & 15;

    __shared__ unsigned short hbuf[4][64 * SROW];
    __shared__ float sc[256];
    __shared__ float wgt[256];
    __shared__ float redbuf[256];

    const float ox = rays_o[3*r+0], oy = rays_o[3*r+1], oz = rays_o[3*r+2];
    float dxv = rays_d[3*r+0], dyv = rays_d[3*r+1], dzv = rays_d[3*r+2];
    const float vdx = viewdirs[3*r+0], vdy = viewdirs[3*r+1], vdz = viewdirs[3*r+2];
    const float rinv = rsqrtf(dxv*dxv + dyv*dyv + dzv*dzv);
    dxv *= rinv; dyv *= rinv; dzv *= rinv;

    float t;
    if (tid < NIN) {
        t = ((float)tid + 0.5f) * (2.0f * 1.7320508075688772f / 231.0f);
    } else {
        const float lstep = 0.999f / 23.0f;
        const int j = tid - NIN;
        const float L0 = 1.0f - (float)j * lstep;
        const float L1 = 1.0f - (float)(j+1) * lstep;
        t = 1.7320508075688772f * (1.0f/L0 + 1.0f/L1);
    }

    float px = fmaf(dxv, t, ox), py = fmaf(dyv, t, oy), pz = fmaf(dzv, t, oz);
    const float nrm = fmaxf(fabsf(px), fmaxf(fabsf(py), fabsf(pz)));
    if (nrm > 1.0f) {
        const float s = (1.2f - 0.2f / nrm) / nrm;
        px *= s; py *= s; pz *= s;
    }

    const float gsc = 159.0f / 2.4f;
    const float gx = fminf(fmaxf((px + 1.2f) * gsc, 0.0f), 159.0f);
    const float gy = fminf(fmaxf((py + 1.2f) * gsc, 0.0f), 159.0f);
    const float gz = fminf(fmaxf((pz + 1.2f) * gsc, 0.0f), 159.0f);
    const int x0 = min((int)gx, GR-2), y0 = min((int)gy, GR-2), z0 = min((int)gz, GR-2);
    const float fx = gx - (float)x0, fy = gy - (float)y0, fz = gz - (float)z0;
    const int base = x0*GR2 + y0*GR + z0;

    const float d000 = dg[base],        d001 = dg[base+1];
    const float d010 = dg[base+GR],     d011 = dg[base+GR+1];
    const float d100 = dg[base+GR2],    d101 = dg[base+GR2+1];
    const float d110 = dg[base+GR2+GR], d111 = dg[base+GR2+GR+1];
    const float c00 = d000*(1.0f-fz) + d001*fz;
    const float c01 = d010*(1.0f-fz) + d011*fz;
    const float c10 = d100*(1.0f-fz) + d101*fz;
    const float c11 = d110*(1.0f-fz) + d111*fz;
    const float dens = (c00*(1.0f-fy) + c01*fy)*(1.0f-fx) + (c10*(1.0f-fy) + c11*fy)*fx;

    const float ACT_SHIFT = -9.21024036697535f;
    const float alpha = (tid < PSAMP) ? sigmoidf_(dens + ACT_SHIFT) : 0.0f;

    sc[tid] = 1.0f - alpha;
    __syncthreads();
    #pragma unroll
    for (int off = 1; off < 256; off <<= 1) {
        const float v = (tid >= off) ? sc[tid - off] : 1.0f;
        __syncthreads();
        sc[tid] *= v;
        __syncthreads();
    }
    const float T_excl = (tid == 0) ? 1.0f : sc[tid-1];
    wgt[tid] = alpha * T_excl;

    const float wx0 = 1.0f-fx, wy0 = 1.0f-fy, wz0 = 1.0f-fz;
    const float w000 = wx0*wy0*wz0, w001 = wx0*wy0*fz, w010 = wx0*fy*wz0, w011 = wx0*fy*fz;
    const float w100 = fx*wy0*wz0,  w101 = fx*wy0*fz,  w110 = fx*fy*wz0,  w111 = fx*fy*fz;

    float fv[40];
    #pragma unroll
    for (int c = 0; c < 12; c++) {
        const float* g = k0g + c*GR3 + base;
        fv[c] = w000*g[0]      + w001*g[1]
              + w010*g[GR]     + w011*g[GR+1]
              + w100*g[GR2]    + w101*g[GR2+1]
              + w110*g[GR2+GR] + w111*g[GR2+GR+1];
    }
    fv[12] = vdx; fv[13] = vdy; fv[14] = vdz;
    #pragma unroll
    for (int p = 0; p < 4; p++) {
        const float f = (float)(1 << p);
        fv[15+p] = __sinf(vdx*f);  fv[19+p] = __sinf(vdy*f);  fv[23+p] = __sinf(vdz*f);
        fv[27+p] = __cosf(vdx*f);  fv[31+p] = __cosf(vdy*f);  fv[35+p] = __cosf(vdz*f);
    }
    fv[39] = 0.0f;

    unsigned short* hb = &hbuf[wv][0];
    {
        const int row = tid & 63;
        uint4* dst = (uint4*)(hb + row * SROW);
        #pragma unroll
        for (int i = 0; i < 8; i++) {
            unsigned p[4];
            #pragma unroll
            for (int q = 0; q < 4; q++) {
                const int e0 = i*8 + 2*q, e1 = e0 + 1;
                const unsigned lov = (e0 < 39) ? f2bf(fv[e0]) : 0u;
                const unsigned hiv = (e1 < 39) ? f2bf(fv[e1]) : 0u;
                p[q] = lov | (hiv << 16);
            }
            uint4 v; v.x = p[0]; v.y = p[1]; v.z = p[2]; v.w = p[3];
            dst[i] = v;
        }
    }
    __syncthreads();

    f32x4 acc1[4][8];
    #pragma unroll
    for (int nt = 0; nt < 8; nt++) {
        const float bz = b0[nt*16 + l16];
        #pragma unroll
        for (int mt = 0; mt < 4; mt++) { f32x4 z = {bz,bz,bz,bz}; acc1[mt][nt] = z; }
    }
    #pragma unroll
    for (int ks = 0; ks < 2; ks++) {
        bf16x8 a[4];
        #pragma unroll
        for (int mt = 0; mt < 4; mt++)
            a[mt] = *(const bf16x8*)(hb + (mt*16 + l16)*SROW + ks*32 + quad*8);
        #pragma unroll
        for (int nt = 0; nt < 8; nt++) {
            const bf16x8 b = *(const bf16x8*)(pw0 + ((nt*2 + ks)*64 + lane)*8);
            #pragma unroll
            for (int mt = 0; mt < 4; mt++)
                acc1[mt][nt] = __builtin_amdgcn_mfma_f32_16x16x32_bf16(a[mt], b, acc1[mt][nt], 0,0,0);
        }
    }
    #pragma unroll
    for (int mt = 0; mt < 4; mt++)
        #pragma unroll
        for (int nt = 0; nt < 8; nt++)
            #pragma unroll
            for (int e = 0; e < 4; e++)
                hb[(mt*16 + quad*4 + e)*SROW + nt*16 + l16] = f2bf(fmaxf(acc1[mt][nt][e], 0.0f));
    __syncthreads();

    f32x4 acc2[4][8];
    #pragma unroll
    for (int nt = 0; nt < 8; nt++) {
        const float bz = b1[nt*16 + l16];
        #pragma unroll
        for (int mt = 0; mt < 4; mt++) { f32x4 z = {bz,bz,bz,bz}; acc2[mt][nt] = z; }
    }
    #pragma unroll
    for (int ks = 0; ks < 4; ks++) {
        bf16x8 a[4];
        #pragma unroll
        for (int mt = 0; mt < 4; mt++)
            a[mt] = *(const bf16x8*)(hb + (mt*16 + l16)*SROW + ks*32 + quad*8);
        #pragma unroll
        for (int nt = 0; nt < 8; nt++) {
            const bf16x8 b = *(const bf16x8*)(pw1 + ((nt*4 + ks)*64 + lane)*8);
            #pragma unroll
            for (int mt = 0; mt < 4; mt++)
                acc2[mt][nt] = __builtin_amdgcn_mfma_f32_16x16x32_bf16(a[mt], b, acc2[mt][nt], 0,0,0);
        }
    }
    #pragma unroll
    for (int mt = 0; mt < 4; mt++)
        #pragma unroll
        for (int nt = 0; nt < 8; nt++)
            #pragma unroll
            for (int e = 0; e < 4; e++)
                hb[(mt*16 + quad*4 + e)*SROW + nt*16 + l16] = f2bf(fmaxf(acc2[mt][nt][e], 0.0f));
    __syncthreads();

    f32x4 acc3[4];
    {
        const float bz = (l16 < 3) ? b2[l16] : 0.0f;
        #pragma unroll
        for (int mt = 0; mt < 4; mt++) { f32x4 z = {bz,bz,bz,bz}; acc3[mt] = z; }
    }
    #pragma unroll
    for (int ks = 0; ks < 4; ks++) {
        const bf16x8 b = *(const bf16x8*)(pw2 + (ks*64 + lane)*8);
        #pragma unroll
        for (int mt = 0; mt < 4; mt++) {
            const bf16x8 a = *(const bf16x8*)(hb + (mt*16 + l16)*SROW + ks*32 + quad*8);
            acc3[mt] = __builtin_amdgcn_mfma_f32_16x16x32_bf16(a, b, acc3[mt], 0,0,0);
        }
    }

    float contrib = 0.0f;
    #pragma unroll
    for (int mt = 0; mt < 4; mt++)
        #pragma unroll
        for (int e = 0; e < 4; e++) {
            const float s = sigmoidf_(acc3[mt][e]);
            contrib += wgt[wv*64 + mt*16 + quad*4 + e] * s;
        }
    redbuf[tid] = contrib;
    __syncthreads();
    if (tid < 3) {
        float acc_o = sc[PSAMP-1];
        #pragma unroll
        for (int w = 0; w < 4; w++)
            #pragma unroll
            for (int q = 0; q < 4; q++)
                acc_o += redbuf[w*64 + q*16 + tid];
        out[3*r + tid] = acc_o;
    }
}

extern "C" void kernel_launch(void* const* d_in, const int* in_sizes, int n_in,
                              void* d_out, int out_size, void* d_ws, size_t ws_size,
                              hipStream_t stream) {
    (void)in_sizes; (void)n_in; (void)out_size;
    const size_t PG_BYTES = (size_t)GR3 * 32;            // 131,072,000 B packed fp16 grid
    const size_t PW_BYTES = (size_t)(16 + 32 + 4) * 64 * 8 * 2;   // 53,248 B packed weights

    if (ws_size >= PG_BYTES + PW_BYTES) {
        unsigned short* pg  = (unsigned short*)d_ws;
        unsigned short* pw0 = (unsigned short*)((char*)d_ws + PG_BYTES);
        unsigned short* pw1 = pw0 + 16*64*8;
        unsigned short* pw2 = pw1 + 32*64*8;

        repack_grid<<<GR3/512, 256, 0, stream>>>(
            (const float*)d_in[3], (const float*)d_in[4], pg);
        prepack<<<4, 256, 0, stream>>>((const float*)d_in[5], pw0,  39, 128, 128, 8, 2);
        prepack<<<8, 256, 0, stream>>>((const float*)d_in[7], pw1, 128, 128, 128, 8, 4);
        prepack<<<1, 256, 0, stream>>>((const float*)d_in[9], pw2, 128,   3,   3, 1, 4);

        voxgo_mfma_pk<<<NRAYS, 256, 0, stream>>>(
            (const float*)d_in[0], (const float*)d_in[1], (const float*)d_in[2],
            pg,
            (const float*)d_in[6], (const float*)d_in[8], (const float*)d_in[10],
            pw0, pw1, pw2,
            (float*)d_out);
    } else {
        unsigned short* pw0 = (unsigned short*)d_ws;
        unsigned short* pw1 = pw0 + 16*64*8;
        unsigned short* pw2 = pw1 + 32*64*8;

        prepack<<<4, 256, 0, stream>>>((const float*)d_in[5], pw0,  39, 128, 128, 8, 2);
        prepack<<<8, 256, 0, stream>>>((const float*)d_in[7], pw1, 128, 128, 128, 8, 4);
        prepack<<<1, 256, 0, stream>>>((const float*)d_in[9], pw2, 128,   3,   3, 1, 4);

        voxgo_mfma_f32<<<NRAYS, 256, 0, stream>>>(
            (const float*)d_in[0], (const float*)d_in[1], (const float*)d_in[2],
            (const float*)d_in[3], (const float*)d_in[4],
            (const float*)d_in[6], (const float*)d_in[8], (const float*)d_in[10],
            pw0, pw1, pw2,
            (float*)d_out);
    }
}